// Round 1
// baseline (79.637 us; speedup 1.0000x reference)
//
#include <hip/hip_runtime.h>
#include <math.h>

#define GMM_K 8
#define HALF_LOG2PI 0.9189385332046727f  // 0.5 * log(2*pi)

__global__ __launch_bounds__(256) void gmm_hscore_kernel(
    const float* __restrict__ x,
    const float* __restrict__ mean,
    const float* __restrict__ logvar,
    const float* __restrict__ logweight,
    float* __restrict__ out,
    int n)   // n = number of points
{
    __shared__ float s_mu[GMM_K];
    __shared__ float s_iv[GMM_K];   // 1/var
    __shared__ float s_C[GMM_K];    // exp(logw - 0.5*lv - 0.5*log2pi)

    const int t = threadIdx.x;
    if (t < GMM_K) {
        float lv = logvar[t];
        s_mu[t] = mean[t];
        s_iv[t] = __expf(-lv);
        s_C[t]  = __expf(logweight[t] - 0.5f * lv - HALF_LOG2PI);
    }
    __syncthreads();

    const int idx = blockIdx.x * blockDim.x + t;   // float4 index
    const int base = idx * 4;
    if (base >= n) return;

    float xs[4];
    float res[4];
    int cnt;
    if (base + 3 < n) {
        float4 xv = ((const float4*)x)[idx];
        xs[0] = xv.x; xs[1] = xv.y; xs[2] = xv.z; xs[3] = xv.w;
        cnt = 4;
    } else {
        cnt = n - base;
        for (int j = 0; j < cnt; ++j) xs[j] = x[base + j];
    }

#pragma unroll
    for (int j = 0; j < 4; ++j) {
        float xx = xs[j];
        float mpdf = 0.0f, mdpdf = 0.0f, ddpdf = 0.0f;
#pragma unroll
        for (int k = 0; k < GMM_K; ++k) {
            float iv   = s_iv[k];
            float diff = xx - s_mu[k];
            float sd   = diff * iv;                      // diff / var
            float p    = s_C[k] * __expf(-0.5f * diff * sd);
            float s    = -sd;
            mpdf  += p;
            mdpdf += p * s;
            ddpdf += p * (s * s - iv);
        }
        float inv_m = __builtin_amdgcn_rcpf(mpdf);
        float dln   = mdpdf * inv_m;
        res[j] = -0.5f * dln * dln + ddpdf * inv_m;
    }

    if (base + 3 < n) {
        ((float4*)out)[idx] = make_float4(res[0], res[1], res[2], res[3]);
    } else {
        for (int j = 0; j < cnt; ++j) out[base + j] = res[j];
    }
}

extern "C" void kernel_launch(void* const* d_in, const int* in_sizes, int n_in,
                              void* d_out, int out_size, void* d_ws, size_t ws_size,
                              hipStream_t stream) {
    const float* x         = (const float*)d_in[0];
    const float* mean      = (const float*)d_in[1];
    const float* logvar    = (const float*)d_in[2];
    const float* logweight = (const float*)d_in[3];
    float* out = (float*)d_out;

    const int n  = in_sizes[0];            // 4194304 points
    const int n4 = (n + 3) / 4;            // float4 groups
    const int block = 256;
    const int grid  = (n4 + block - 1) / block;

    gmm_hscore_kernel<<<grid, block, 0, stream>>>(x, mean, logvar, logweight, out, n);
}

// Round 2
// 77.137 us; speedup vs baseline: 1.0324x; 1.0324x over previous
//
#include <hip/hip_runtime.h>
#include <math.h>

#define GMM_K 8
#define HALF_LOG2PI 0.9189385332046727f   // 0.5 * log(2*pi)
#define LOG2E       1.4426950408889634f   // 1/ln(2)

// Per point: hscore = -0.5*(mdpdf/mpdf)^2 + ddpdf/mpdf with
//   p_k  = exp2( c1_k + c2_k * diff^2 ),  c1_k = (logw_k - 0.5*lv_k - 0.5*log2pi)*log2e
//                                          c2_k = -0.5*log2e * iv_k,  iv_k = exp(-lv_k)
//   sd   = diff * iv_k
//   mpdf += p ; md += p*sd (true mdpdf = -md) ; dd += p*(sd^2 - iv)
// 8 points/thread, float4 x2 vector I/O. Params broadcast from LDS (conflict-free).
__global__ __launch_bounds__(256) void gmm_hscore_kernel(
    const float* __restrict__ x,
    const float* __restrict__ mean,
    const float* __restrict__ logvar,
    const float* __restrict__ logweight,
    float* __restrict__ out,
    int n)
{
    __shared__ float s_mu[GMM_K];
    __shared__ float s_iv[GMM_K];
    __shared__ float s_c1[GMM_K];
    __shared__ float s_c2[GMM_K];

    const int t = threadIdx.x;
    if (t < GMM_K) {
        float lv = logvar[t];
        float iv = __expf(-lv);
        s_mu[t] = mean[t];
        s_iv[t] = iv;
        s_c1[t] = (logweight[t] - 0.5f * lv - HALF_LOG2PI) * LOG2E;
        s_c2[t] = -0.5f * LOG2E * iv;
    }
    __syncthreads();

    const int tid  = blockIdx.x * blockDim.x + t;   // 8-point group index
    const int base = tid * 8;
    if (base >= n) return;

    if (base + 7 < n) {
        const float4* xv = (const float4*)x;
        float4 a = xv[tid * 2];
        float4 b = xv[tid * 2 + 1];
        float xs[8] = {a.x, a.y, a.z, a.w, b.x, b.y, b.z, b.w};
        float res[8];

#pragma unroll
        for (int j = 0; j < 8; ++j) {
            float xx = xs[j];
            float m = 0.0f, md = 0.0f, dd = 0.0f;
#pragma unroll
            for (int k = 0; k < GMM_K; ++k) {
                float mu = s_mu[k];
                float iv = s_iv[k];
                float diff = xx - mu;
                float d2   = diff * diff;
                float p    = __builtin_amdgcn_exp2f(__builtin_fmaf(s_c2[k], d2, s_c1[k]));
                float sd   = diff * iv;
                m  += p;
                md = __builtin_fmaf(p, sd, md);                         // = -mdpdf
                dd = __builtin_fmaf(p, __builtin_fmaf(sd, sd, -iv), dd);
            }
            float inv_m = __builtin_amdgcn_rcpf(m);
            float dln   = md * inv_m;                                    // |dlnpdf|
            res[j] = __builtin_fmaf(-0.5f * dln, dln, dd * inv_m);
        }

        float4* ov = (float4*)out;
        ov[tid * 2]     = make_float4(res[0], res[1], res[2], res[3]);
        ov[tid * 2 + 1] = make_float4(res[4], res[5], res[6], res[7]);
    } else {
        // tail (not hit for N=4194304, kept for generality)
        for (int i = base; i < n; ++i) {
            float xx = x[i];
            float m = 0.0f, md = 0.0f, dd = 0.0f;
            for (int k = 0; k < GMM_K; ++k) {
                float diff = xx - s_mu[k];
                float d2   = diff * diff;
                float p    = __builtin_amdgcn_exp2f(__builtin_fmaf(s_c2[k], d2, s_c1[k]));
                float sd   = diff * s_iv[k];
                m  += p;
                md = __builtin_fmaf(p, sd, md);
                dd = __builtin_fmaf(p, __builtin_fmaf(sd, sd, -s_iv[k]), dd);
            }
            float inv_m = __builtin_amdgcn_rcpf(m);
            float dln   = md * inv_m;
            out[i] = __builtin_fmaf(-0.5f * dln, dln, dd * inv_m);
        }
    }
}

extern "C" void kernel_launch(void* const* d_in, const int* in_sizes, int n_in,
                              void* d_out, int out_size, void* d_ws, size_t ws_size,
                              hipStream_t stream) {
    const float* x         = (const float*)d_in[0];
    const float* mean      = (const float*)d_in[1];
    const float* logvar    = (const float*)d_in[2];
    const float* logweight = (const float*)d_in[3];
    float* out = (float*)d_out;

    const int n = in_sizes[0];                 // 4194304 points
    const int pts_per_block = 256 * 8;
    const int grid = (n + pts_per_block - 1) / pts_per_block;   // 2048 blocks

    gmm_hscore_kernel<<<grid, 256, 0, stream>>>(x, mean, logvar, logweight, out, n);
}